// Round 7
// baseline (304.766 us; speedup 1.0000x reference)
//
#include <hip/hip_runtime.h>

// Problem constants (fixed by setup_inputs)
#define T_   16
#define TOK_ 16384
#define P_   8192
#define N_   32768
#define D_   128
#define L_   8
#define C_   16

typedef float f32x4 __attribute__((ext_vector_type(4)));

constexpr int K1_BLOCKS     = 2048;
constexpr int BLOCKS_PER_T  = 128;   // K1 blocks per timestamp
constexpr int ROWS_PER_WAVE = 16;    // 8192 rows / (128 blocks * 4 waves)

// ---------------------------------------------------------------------------
// Kernel 1 (fused): per block, gather 64 x-rows at node_pos, LN(D=128) with
// algebraically-fused 8->1 pool, per-group-l accumulate -> partial[b][128].
// Then last-block-per-t (atomic ticket) finalizes: reduce 128 chunks, scale,
// LN(128, g_fin/b_fin), per-16 LN (g_dec/b_dec) -> decoded[t*128+..].
// ---------------------------------------------------------------------------
__global__ __launch_bounds__(256) void k1_fused(
    const float* __restrict__ x,
    const float* __restrict__ g_enc, const float* __restrict__ b_enc,
    const float* __restrict__ g_fin, const float* __restrict__ b_fin,
    const float* __restrict__ g_dec, const float* __restrict__ b_dec,
    const int* __restrict__ node_pos, const int* __restrict__ node_ids,
    float* __restrict__ partial, float* __restrict__ decoded,
    int* __restrict__ counters)
{
    __shared__ float lds[4 * 128];
    __shared__ int win;
    const int tid   = threadIdx.x;
    const int lane  = tid & 63;
    const int wid   = tid >> 6;
    const int j     = lane & 15;   // channel sublane
    const int q     = lane >> 4;   // quarter (row within batch)
    const int b     = blockIdx.x;
    const int t     = b >> 7;      // 128 blocks per t
    const int chunk = b & 127;
    const int pbase = chunk * 64 + wid * ROWS_PER_WAVE;
    const int tP    = t * P_;
    const float* xt = x + (size_t)t * TOK_ * D_;

    // ---- phase A: gather + LN + pool + group-accumulate (R4-proven) -------
    {
        const f32x4 g0  = *(const f32x4*)(g_enc + 8 * j);
        const f32x4 g1  = *(const f32x4*)(g_enc + 8 * j + 4);
        const f32x4 bb0 = *(const f32x4*)(b_enc + 8 * j);
        const f32x4 bb1 = *(const f32x4*)(b_enc + 8 * j + 4);
        const float G = g0.x + g0.y + g0.z + g0.w + g1.x + g1.y + g1.z + g1.w;
        const float B = bb0.x + bb0.y + bb0.z + bb0.w + bb1.x + bb1.y + bb1.z + bb1.w;

        const int posv = node_pos[tP + pbase + j];
        const int nidv = node_ids[tP + pbase + j];

        f32x4 va[4], vb[4];
#pragma unroll
        for (int i = 0; i < 4; ++i) {
            const int p = __shfl(posv, i * 4 + q);
            const float* row = xt + (size_t)p * D_ + 8 * j;
            va[i] = *(const f32x4*)(row);
            vb[i] = *(const f32x4*)(row + 4);
        }

        float acc[L_];
#pragma unroll
        for (int ll = 0; ll < L_; ++ll) acc[ll] = 0.f;

#pragma unroll
        for (int i = 0; i < 4; ++i) {
            const f32x4 a = va[i], c = vb[i];
            float s  = a.x + a.y + a.z + a.w + c.x + c.y + c.z + c.w;
            float ss = a.x*a.x + a.y*a.y + a.z*a.z + a.w*a.w
                     + c.x*c.x + c.y*c.y + c.z*c.z + c.w*c.w;
            float dot = a.x*g0.x + a.y*g0.y + a.z*g0.z + a.w*g0.w
                      + c.x*g1.x + c.y*g1.y + c.z*g1.z + c.w*g1.w;
#pragma unroll
            for (int m = 1; m < 16; m <<= 1) {
                s  += __shfl_xor(s, m);
                ss += __shfl_xor(ss, m);
            }
            const float mean = s * (1.f / 128.f);
            const float rstd = rsqrtf(ss * (1.f / 128.f) - mean * mean + 1e-5f);
            const float srow = (dot - mean * G) * rstd + B;
            const int l = __shfl(nidv, i * 4 + q) >> 12;
#pragma unroll
            for (int ll = 0; ll < L_; ++ll) acc[ll] += (ll == l) ? srow : 0.f;
        }

#pragma unroll
        for (int ll = 0; ll < L_; ++ll) {
            acc[ll] += __shfl_xor(acc[ll], 16);
            acc[ll] += __shfl_xor(acc[ll], 32);
        }
        if (lane < 16) {
#pragma unroll
            for (int ll = 0; ll < L_; ++ll) lds[wid * 128 + ll * 16 + j] = acc[ll];
        }
        __syncthreads();
        if (tid < 128) {
            const float sum = lds[tid] + lds[128 + tid] + lds[256 + tid] + lds[384 + tid];
            partial[(size_t)b * 128 + tid] = sum;
        }
    }

    // ---- last-block ticket -------------------------------------------------
    __threadfence();                 // order my block's partial writes
    __syncthreads();                 // all writers fenced before ticket
    if (tid == 0) {
        const int ret = atomicAdd(&counters[t], 1);
        win = (ret == BLOCKS_PER_T - 1);
        __threadfence();             // acquire side for partial reads below
    }
    __syncthreads();
    if (!win) return;

    // ---- finalize (winner block only, 256-thread parallel) ----------------
    {
        const float* pb = partial + (size_t)t * BLOCKS_PER_T * 128;
        const int ch = tid & 127, h = tid >> 7;
        float a = 0.f;
#pragma unroll 8
        for (int k = 0; k < 64; ++k)
            a += pb[(h * 64 + k) * 128 + ch];
        lds[h * 128 + ch] = a;
        __syncthreads();
        if (tid < 64) {
            const int ln = tid;
            float c0 = (lds[ln] + lds[128 + ln]) * (1.f / 32768.f);
            float c1 = (lds[64 + ln] + lds[192 + ln]) * (1.f / 32768.f);
            float s = c0 + c1, ss = c0 * c0 + c1 * c1;
#pragma unroll
            for (int m = 1; m < 64; m <<= 1) {
                s  += __shfl_xor(s, m);
                ss += __shfl_xor(ss, m);
            }
            const float mean = s * (1.f / 128.f);
            const float rstd = rsqrtf(ss * (1.f / 128.f) - mean * mean + 1e-5f);
            const float e0 = (c0 - mean) * rstd * g_fin[ln]      + b_fin[ln];
            const float e1 = (c1 - mean) * rstd * g_fin[ln + 64] + b_fin[ln + 64];

            float s0 = e0, q0 = e0 * e0, s1 = e1, q1 = e1 * e1;
#pragma unroll
            for (int m = 1; m < 16; m <<= 1) {
                s0 += __shfl_xor(s0, m); q0 += __shfl_xor(q0, m);
                s1 += __shfl_xor(s1, m); q1 += __shfl_xor(q1, m);
            }
            const float m0 = s0 * (1.f / 16.f), m1 = s1 * (1.f / 16.f);
            const float r0 = rsqrtf(q0 * (1.f / 16.f) - m0 * m0 + 1e-5f);
            const float r1 = rsqrtf(q1 * (1.f / 16.f) - m1 * m1 + 1e-5f);
            const int c = ln & 15;
            const float gd = g_dec[c], bd = b_dec[c];
            decoded[t * 128 + ln]      = (e0 - m0) * r0 * gd + bd;
            decoded[t * 128 + 64 + ln] = (e1 - m1) * r1 * gd + bd;
        }
    }
}

// ---------------------------------------------------------------------------
// Kernel 3: out[t,n,d] = decoded[t, n>>12, d>>3].
// 2048 blocks; block b covers one contiguous 128 KB slice of one (t, l).
// Per-thread value is constant -> pure NONTEMPORAL store stream (R6 A/B:
// nt beats plain by ~8.4 us on this kernel).
// ---------------------------------------------------------------------------
__global__ __launch_bounds__(256) void k3_broadcast(
    const float* __restrict__ decoded, f32x4* __restrict__ out)
{
    const int tid   = threadIdx.x;
    const int b     = blockIdx.x;
    const int t     = b >> 7;
    const int chunk = b & 127;
    const int l     = chunk >> 4;                 // 16 blocks per l-group
    const float val = decoded[(t << 7) + (l << 4) + ((tid & 31) >> 1)];
    const f32x4 v4 = {val, val, val, val};
    f32x4* p = out + (((size_t)t << 20) + ((size_t)chunk << 13) + tid);
#pragma unroll
    for (int it = 0; it < 32; ++it)
        __builtin_nontemporal_store(v4, p + (it << 8));
}

extern "C" void kernel_launch(void* const* d_in, const int* in_sizes, int n_in,
                              void* d_out, int out_size, void* d_ws, size_t ws_size,
                              hipStream_t stream)
{
    const float* x      = (const float*)d_in[0];
    const float* g_enc  = (const float*)d_in[1];
    const float* b_enc  = (const float*)d_in[2];
    const float* g_fin  = (const float*)d_in[3];
    const float* b_fin  = (const float*)d_in[4];
    const float* g_dec  = (const float*)d_in[5];
    const float* b_dec  = (const float*)d_in[6];
    const int*   node_pos = (const int*)d_in[7];
    const int*   node_ids = (const int*)d_in[8];

    float* partial = (float*)d_ws;                         // 2048*128 f32 = 1 MB
    float* decoded = partial + (size_t)K1_BLOCKS * 128;    // 2048 f32
    int*   counters = (int*)(decoded + T_ * 128);          // 16 ints
    float* out = (float*)d_out;

    hipMemsetAsync(counters, 0, T_ * sizeof(int), stream); // ws not re-poisoned
    hipLaunchKernelGGL(k1_fused, dim3(K1_BLOCKS), dim3(256), 0, stream,
                       x, g_enc, b_enc, g_fin, b_fin, g_dec, b_dec,
                       node_pos, node_ids, partial, decoded, counters);
    hipLaunchKernelGGL(k3_broadcast, dim3(2048), dim3(256), 0, stream,
                       decoded, (f32x4*)out);
}

// Round 8
// 104.681 us; speedup vs baseline: 2.9114x; 2.9114x over previous
//
#include <hip/hip_runtime.h>

// Problem constants (fixed by setup_inputs)
#define T_   16
#define TOK_ 16384
#define P_   8192
#define N_   32768
#define D_   128
#define L_   8
#define C_   16

typedef float f32x2 __attribute__((ext_vector_type(2)));
typedef float f32x4 __attribute__((ext_vector_type(4)));

constexpr int K1_BLOCKS     = 2048;
constexpr int BLOCKS_PER_T  = 128;   // K1 producer blocks per timestamp
constexpr int ROWS_PER_WAVE = 16;    // 8192 rows / (128 blocks * 4 waves)

// ---------------------------------------------------------------------------
// Kernel 1: gather x rows at node_pos, LayerNorm over D=128 (g_enc,b_enc),
// pool 8->1, accumulate per group l = node_id>>12 into per-block partials.
// (R4-proven structure; launched 3x this round as a timing probe — each
// launch writes identical values to `partial`, so output is unchanged.)
// ---------------------------------------------------------------------------
__global__ __launch_bounds__(256) void k1_gather_ln_pool(
    const float* __restrict__ x,
    const float* __restrict__ g_enc, const float* __restrict__ b_enc,
    const int* __restrict__ node_pos, const int* __restrict__ node_ids,
    float* __restrict__ partial)
{
    __shared__ float lds[4 * 128];
    const int tid   = threadIdx.x;
    const int lane  = tid & 63;
    const int wid   = tid >> 6;
    const int j     = lane & 15;   // channel
    const int q     = lane >> 4;   // quarter (row within batch)
    const int b     = blockIdx.x;
    const int t     = b >> 7;      // 128 blocks per t
    const int chunk = b & 127;
    const int pbase = chunk * 64 + wid * ROWS_PER_WAVE;
    const int tP    = t * P_;
    const float* xt = x + (size_t)t * TOK_ * D_;

    // per-lane LN params for elements d = 8j..8j+7
    const f32x4 g0  = *(const f32x4*)(g_enc + 8 * j);
    const f32x4 g1  = *(const f32x4*)(g_enc + 8 * j + 4);
    const f32x4 bb0 = *(const f32x4*)(b_enc + 8 * j);
    const f32x4 bb1 = *(const f32x4*)(b_enc + 8 * j + 4);
    const float G = g0.x + g0.y + g0.z + g0.w + g1.x + g1.y + g1.z + g1.w;
    const float B = bb0.x + bb0.y + bb0.z + bb0.w + bb1.x + bb1.y + bb1.z + bb1.w;

    // lanes 0..15 hold the wave's 16 row indices (other lanes duplicate)
    const int posv = node_pos[tP + pbase + j];
    const int nidv = node_ids[tP + pbase + j];

    // issue ALL gather loads up-front: row r = i*4+q, lane reads d=8j..8j+7
    f32x4 va[4], vb[4];
#pragma unroll
    for (int i = 0; i < 4; ++i) {
        const int p = __shfl(posv, i * 4 + q);
        const float* row = xt + (size_t)p * D_ + 8 * j;
        va[i] = *(const f32x4*)(row);
        vb[i] = *(const f32x4*)(row + 4);
    }

    float acc[L_];
#pragma unroll
    for (int ll = 0; ll < L_; ++ll) acc[ll] = 0.f;

#pragma unroll
    for (int i = 0; i < 4; ++i) {
        const f32x4 a = va[i], c = vb[i];
        float s  = a.x + a.y + a.z + a.w + c.x + c.y + c.z + c.w;
        float ss = a.x*a.x + a.y*a.y + a.z*a.z + a.w*a.w
                 + c.x*c.x + c.y*c.y + c.z*c.z + c.w*c.w;
        float dot = a.x*g0.x + a.y*g0.y + a.z*g0.z + a.w*g0.w
                  + c.x*g1.x + c.y*g1.y + c.z*g1.z + c.w*g1.w;
        // LN stats over the row's 128 elements: reduce across 16 lanes
#pragma unroll
        for (int m = 1; m < 16; m <<= 1) {
            s  += __shfl_xor(s, m);
            ss += __shfl_xor(ss, m);
        }
        const float mean = s * (1.f / 128.f);
        const float rstd = rsqrtf(ss * (1.f / 128.f) - mean * mean + 1e-5f);
        const float srow = (dot - mean * G) * rstd + B;   // channel-c pooled sum
        const int l = __shfl(nidv, i * 4 + q) >> 12;
#pragma unroll
        for (int ll = 0; ll < L_; ++ll) acc[ll] += (ll == l) ? srow : 0.f;
    }

    // combine quarters (lanes j, j+16, j+32, j+48 share channel j)
#pragma unroll
    for (int ll = 0; ll < L_; ++ll) {
        acc[ll] += __shfl_xor(acc[ll], 16);
        acc[ll] += __shfl_xor(acc[ll], 32);
    }
    if (lane < 16) {
#pragma unroll
        for (int ll = 0; ll < L_; ++ll) lds[wid * 128 + ll * 16 + j] = acc[ll];
    }
    __syncthreads();
    if (tid < 128) {
        const float sum = lds[tid] + lds[128 + tid] + lds[256 + tid] + lds[384 + tid];
        partial[(size_t)b * 128 + tid] = sum;   // deterministic overwrite
    }
}

// ---------------------------------------------------------------------------
// Kernel 2: reduce 128 partials per t, scale, LN over 128 (g_fin,b_fin),
// LN over 16-element groups (g_dec,b_dec) -> decoded[t*128 + l*16 + c]
// (launched 3x this round; identical writes each time)
// ---------------------------------------------------------------------------
__global__ __launch_bounds__(64) void k2_finalize(
    const float* __restrict__ partial,
    const float* __restrict__ g_fin, const float* __restrict__ b_fin,
    const float* __restrict__ g_dec, const float* __restrict__ b_dec,
    float* __restrict__ decoded)
{
    const int t = blockIdx.x;
    const int lane = threadIdx.x;
    const float* pb = partial + (size_t)t * BLOCKS_PER_T * 128;
    float a0 = 0.f, a1 = 0.f;
#pragma unroll 8
    for (int k = 0; k < BLOCKS_PER_T; ++k) {
        a0 += pb[k * 128 + lane];
        a1 += pb[k * 128 + 64 + lane];
    }
    a0 *= (1.f / 32768.f);   // /4096 scatter slots /8 pooled
    a1 *= (1.f / 32768.f);

    float s = a0 + a1, ss = a0 * a0 + a1 * a1;
#pragma unroll
    for (int m = 1; m < 64; m <<= 1) {
        s  += __shfl_xor(s, m);
        ss += __shfl_xor(ss, m);
    }
    const float mean = s * (1.f / 128.f);
    const float rstd = rsqrtf(ss * (1.f / 128.f) - mean * mean + 1e-5f);
    const float c0 = (a0 - mean) * rstd * g_fin[lane]      + b_fin[lane];
    const float c1 = (a1 - mean) * rstd * g_fin[lane + 64] + b_fin[lane + 64];

    float s0 = c0, q0 = c0 * c0, s1 = c1, q1 = c1 * c1;
#pragma unroll
    for (int m = 1; m < 16; m <<= 1) {
        s0 += __shfl_xor(s0, m); q0 += __shfl_xor(q0, m);
        s1 += __shfl_xor(s1, m); q1 += __shfl_xor(q1, m);
    }
    const float m0 = s0 * (1.f / 16.f), m1 = s1 * (1.f / 16.f);
    const float r0 = rsqrtf(q0 * (1.f / 16.f) - m0 * m0 + 1e-5f);
    const float r1 = rsqrtf(q1 * (1.f / 16.f) - m1 * m1 + 1e-5f);
    const int c = lane & 15;
    const float gd = g_dec[c], bd = b_dec[c];
    decoded[t * 128 + lane]      = (c0 - m0) * r0 * gd + bd;
    decoded[t * 128 + 64 + lane] = (c1 - m1) * r1 * gd + bd;
}

// ---------------------------------------------------------------------------
// Kernel 3: out[t,n,d] = decoded[t, n>>12, d>>3].
// Per-thread-constant value -> pure NONTEMPORAL store stream (R6 A/B:
// nt beats plain by ~8.4 us).
// ---------------------------------------------------------------------------
__global__ __launch_bounds__(256) void k3_broadcast(
    const float* __restrict__ decoded, f32x4* __restrict__ out)
{
    const int tid   = threadIdx.x;
    const int b     = blockIdx.x;
    const int t     = b >> 7;
    const int chunk = b & 127;
    const int l     = chunk >> 4;                 // 16 blocks per l-group
    const float val = decoded[(t << 7) + (l << 4) + ((tid & 31) >> 1)];
    const f32x4 v4 = {val, val, val, val};
    f32x4* p = out + (((size_t)t << 20) + ((size_t)chunk << 13) + tid);
#pragma unroll
    for (int it = 0; it < 32; ++it)
        __builtin_nontemporal_store(v4, p + (it << 8));
}

extern "C" void kernel_launch(void* const* d_in, const int* in_sizes, int n_in,
                              void* d_out, int out_size, void* d_ws, size_t ws_size,
                              hipStream_t stream)
{
    const float* x      = (const float*)d_in[0];
    const float* g_enc  = (const float*)d_in[1];
    const float* b_enc  = (const float*)d_in[2];
    const float* g_fin  = (const float*)d_in[3];
    const float* b_fin  = (const float*)d_in[4];
    const float* g_dec  = (const float*)d_in[5];
    const float* b_dec  = (const float*)d_in[6];
    const int*   node_pos = (const int*)d_in[7];
    const int*   node_ids = (const int*)d_in[8];

    float* partial = (float*)d_ws;                         // 2048*128 f32 = 1 MB
    float* decoded = partial + (size_t)K1_BLOCKS * 128;    // 2048 f32
    float* out = (float*)d_out;

    // --- timing probe: K1 x3 and K2 x3 (identical writes; output unchanged).
    // T1 - T_R4 = 2*K1 + 2*K2 + 4*gap  ->  resolves the K1 / K3 split.
    for (int rep = 0; rep < 3; ++rep)
        hipLaunchKernelGGL(k1_gather_ln_pool, dim3(K1_BLOCKS), dim3(256), 0, stream,
                           x, g_enc, b_enc, node_pos, node_ids, partial);
    for (int rep = 0; rep < 3; ++rep)
        hipLaunchKernelGGL(k2_finalize, dim3(T_), dim3(64), 0, stream,
                           partial, g_fin, b_fin, g_dec, b_dec, decoded);
    hipLaunchKernelGGL(k3_broadcast, dim3(2048), dim3(256), 0, stream,
                       decoded, (f32x4*)out);
}

// Round 9
// 71.360 us; speedup vs baseline: 4.2708x; 1.4669x over previous
//
#include <hip/hip_runtime.h>

// Problem constants (fixed by setup_inputs)
#define T_   16
#define TOK_ 16384
#define P_   8192
#define N_   32768
#define D_   128
#define L_   8
#define C_   16

typedef float f32x4 __attribute__((ext_vector_type(4)));

constexpr int K1_BLOCKS     = 1024;  // 4/CU; longer-lived blocks amortize dispatch ramp
constexpr int BLOCKS_PER_T  = 64;    // K1 blocks per timestamp
constexpr int K3_BLOCKS     = 512;   // exactly 2/CU; each streams 512 KB

// ---------------------------------------------------------------------------
// Kernel 1: gather x rows at node_pos, LN(D=128) with algebraically-fused
// 8->1 pool, per-group-l accumulate -> partial[b][128].
// 16 lanes per row; 32 rows per wave in two 16-row passes; all 8 gather
// loads per pass issue up-front (one memory round-trip each).
// ---------------------------------------------------------------------------
__global__ __launch_bounds__(256) void k1_gather_ln_pool(
    const float* __restrict__ x,
    const float* __restrict__ g_enc, const float* __restrict__ b_enc,
    const int* __restrict__ node_pos, const int* __restrict__ node_ids,
    float* __restrict__ partial)
{
    __shared__ float lds[4 * 128];
    const int tid   = threadIdx.x;
    const int lane  = tid & 63;
    const int wid   = tid >> 6;
    const int j     = lane & 15;   // channel sublane
    const int q     = lane >> 4;   // quarter (row within 4-row batch)
    const int b     = blockIdx.x;
    const int t     = b >> 6;      // 64 blocks per t
    const int chunk = b & 63;
    const int tP    = t * P_;
    const float* xt = x + (size_t)t * TOK_ * D_;

    const f32x4 g0  = *(const f32x4*)(g_enc + 8 * j);
    const f32x4 g1  = *(const f32x4*)(g_enc + 8 * j + 4);
    const f32x4 bb0 = *(const f32x4*)(b_enc + 8 * j);
    const f32x4 bb1 = *(const f32x4*)(b_enc + 8 * j + 4);
    const float G = g0.x + g0.y + g0.z + g0.w + g1.x + g1.y + g1.z + g1.w;
    const float B = bb0.x + bb0.y + bb0.z + bb0.w + bb1.x + bb1.y + bb1.z + bb1.w;

    float acc[L_];
#pragma unroll
    for (int ll = 0; ll < L_; ++ll) acc[ll] = 0.f;

#pragma unroll
    for (int pass = 0; pass < 2; ++pass) {
        const int pbase = chunk * 128 + pass * 64 + wid * 16;
        // lanes 0..15 hold this pass's 16 row indices (others duplicate)
        const int posv = node_pos[tP + pbase + j];
        const int nidv = node_ids[tP + pbase + j];

        // issue ALL 8 gather loads up-front (row r=i*4+q, d=8j..8j+7)
        f32x4 va[4], vb[4];
#pragma unroll
        for (int i = 0; i < 4; ++i) {
            const int p = __shfl(posv, i * 4 + q);
            const float* row = xt + (size_t)p * D_ + 8 * j;
            va[i] = *(const f32x4*)(row);
            vb[i] = *(const f32x4*)(row + 4);
        }
#pragma unroll
        for (int i = 0; i < 4; ++i) {
            const f32x4 a = va[i], c = vb[i];
            float s  = a.x + a.y + a.z + a.w + c.x + c.y + c.z + c.w;
            float ss = a.x*a.x + a.y*a.y + a.z*a.z + a.w*a.w
                     + c.x*c.x + c.y*c.y + c.z*c.z + c.w*c.w;
            float dot = a.x*g0.x + a.y*g0.y + a.z*g0.z + a.w*g0.w
                      + c.x*g1.x + c.y*g1.y + c.z*g1.z + c.w*g1.w;
#pragma unroll
            for (int m = 1; m < 16; m <<= 1) {
                s  += __shfl_xor(s, m);
                ss += __shfl_xor(ss, m);
            }
            const float mean = s * (1.f / 128.f);
            const float rstd = rsqrtf(ss * (1.f / 128.f) - mean * mean + 1e-5f);
            const float srow = (dot - mean * G) * rstd + B;
            const int l = __shfl(nidv, i * 4 + q) >> 12;
#pragma unroll
            for (int ll = 0; ll < L_; ++ll) acc[ll] += (ll == l) ? srow : 0.f;
        }
    }

    // combine quarters (lanes j, j+16, j+32, j+48 share channel j)
#pragma unroll
    for (int ll = 0; ll < L_; ++ll) {
        acc[ll] += __shfl_xor(acc[ll], 16);
        acc[ll] += __shfl_xor(acc[ll], 32);
    }
    if (lane < 16) {
#pragma unroll
        for (int ll = 0; ll < L_; ++ll) lds[wid * 128 + ll * 16 + j] = acc[ll];
    }
    __syncthreads();
    if (tid < 128) {
        const float sum = lds[tid] + lds[128 + tid] + lds[256 + tid] + lds[384 + tid];
        partial[(size_t)b * 128 + tid] = sum;   // deterministic overwrite
    }
}

// ---------------------------------------------------------------------------
// Kernel 2: reduce 64 partials per t, scale, LN over 128 (g_fin,b_fin),
// LN over 16-element groups (g_dec,b_dec) -> decoded[t*128 + l*16 + c]
// ---------------------------------------------------------------------------
__global__ __launch_bounds__(64) void k2_finalize(
    const float* __restrict__ partial,
    const float* __restrict__ g_fin, const float* __restrict__ b_fin,
    const float* __restrict__ g_dec, const float* __restrict__ b_dec,
    float* __restrict__ decoded)
{
    const int t = blockIdx.x;
    const int lane = threadIdx.x;
    const float* pb = partial + (size_t)t * BLOCKS_PER_T * 128;
    float a0 = 0.f, a1 = 0.f;
#pragma unroll 8
    for (int k = 0; k < BLOCKS_PER_T; ++k) {
        a0 += pb[k * 128 + lane];
        a1 += pb[k * 128 + 64 + lane];
    }
    a0 *= (1.f / 32768.f);   // /4096 scatter slots /8 pooled
    a1 *= (1.f / 32768.f);

    float s = a0 + a1, ss = a0 * a0 + a1 * a1;
#pragma unroll
    for (int m = 1; m < 64; m <<= 1) {
        s  += __shfl_xor(s, m);
        ss += __shfl_xor(ss, m);
    }
    const float mean = s * (1.f / 128.f);
    const float rstd = rsqrtf(ss * (1.f / 128.f) - mean * mean + 1e-5f);
    const float c0 = (a0 - mean) * rstd * g_fin[lane]      + b_fin[lane];
    const float c1 = (a1 - mean) * rstd * g_fin[lane + 64] + b_fin[lane + 64];

    float s0 = c0, q0 = c0 * c0, s1 = c1, q1 = c1 * c1;
#pragma unroll
    for (int m = 1; m < 16; m <<= 1) {
        s0 += __shfl_xor(s0, m); q0 += __shfl_xor(q0, m);
        s1 += __shfl_xor(s1, m); q1 += __shfl_xor(q1, m);
    }
    const float m0 = s0 * (1.f / 16.f), m1 = s1 * (1.f / 16.f);
    const float r0 = rsqrtf(q0 * (1.f / 16.f) - m0 * m0 + 1e-5f);
    const float r1 = rsqrtf(q1 * (1.f / 16.f) - m1 * m1 + 1e-5f);
    const int c = lane & 15;
    const float gd = g_dec[c], bd = b_dec[c];
    decoded[t * 128 + lane]      = (c0 - m0) * r0 * gd + bd;
    decoded[t * 128 + 64 + lane] = (c1 - m1) * r1 * gd + bd;
}

// ---------------------------------------------------------------------------
// Kernel 3: out[t,n,d] = decoded[t, n>>12, d>>3].
// 512 long-lived blocks (exactly 2/CU). Block b: t=b>>5, s=b&31 covers rows
// [s*1024,(s+1)*1024) — one l = s>>2. Per-thread value constant (d4 = tid&31
// since 256 | stride). 128 nontemporal f32x4 stores per thread (R6 A/B:
// nt > plain by ~8 us). Long blocks amortize the dispatch ramp (R8 probe:
// K3 had ~20 us of non-streaming time with 2048 short blocks).
// ---------------------------------------------------------------------------
__global__ __launch_bounds__(256) void k3_broadcast(
    const float* __restrict__ decoded, f32x4* __restrict__ out)
{
    const int tid = threadIdx.x;
    const int b   = blockIdx.x;
    const int t   = b >> 5;
    const int s   = b & 31;
    const int l   = s >> 2;
    const float val = decoded[(t << 7) + (l << 4) + ((tid & 31) >> 1)];
    const f32x4 v4 = {val, val, val, val};
    f32x4* p = out + (((size_t)t << 20) + ((size_t)s << 15) + tid);
#pragma unroll 8
    for (int it = 0; it < 128; ++it)
        __builtin_nontemporal_store(v4, p + (it << 8));
}

extern "C" void kernel_launch(void* const* d_in, const int* in_sizes, int n_in,
                              void* d_out, int out_size, void* d_ws, size_t ws_size,
                              hipStream_t stream)
{
    const float* x      = (const float*)d_in[0];
    const float* g_enc  = (const float*)d_in[1];
    const float* b_enc  = (const float*)d_in[2];
    const float* g_fin  = (const float*)d_in[3];
    const float* b_fin  = (const float*)d_in[4];
    const float* g_dec  = (const float*)d_in[5];
    const float* b_dec  = (const float*)d_in[6];
    const int*   node_pos = (const int*)d_in[7];
    const int*   node_ids = (const int*)d_in[8];

    float* partial = (float*)d_ws;                         // 1024*128 f32 = 512 KB
    float* decoded = partial + (size_t)K1_BLOCKS * 128;    // 2048 f32
    float* out = (float*)d_out;

    hipLaunchKernelGGL(k1_gather_ln_pool, dim3(K1_BLOCKS), dim3(256), 0, stream,
                       x, g_enc, b_enc, node_pos, node_ids, partial);
    hipLaunchKernelGGL(k2_finalize, dim3(T_), dim3(64), 0, stream,
                       partial, g_fin, b_fin, g_dec, b_dec, decoded);
    hipLaunchKernelGGL(k3_broadcast, dim3(K3_BLOCKS), dim3(256), 0, stream,
                       decoded, (f32x4*)out);
}

// Round 10
// 70.876 us; speedup vs baseline: 4.3000x; 1.0068x over previous
//
#include <hip/hip_runtime.h>

// Problem constants (fixed by setup_inputs)
#define T_   16
#define TOK_ 16384
#define P_   8192
#define N_   32768
#define D_   128
#define L_   8
#define C_   16

typedef float f32x4 __attribute__((ext_vector_type(4)));

constexpr int K1_BLOCKS     = 1024;  // 4/CU
constexpr int BLOCKS_PER_T  = 64;    // K1 blocks per timestamp
constexpr int K3_BLOCKS     = 512;   // 2/CU; each block streams 512 KB

// ---------------------------------------------------------------------------
// Kernel 1: gather x rows at node_pos, LN(D=128) with algebraically-fused
// 8->1 pool, per-group-l accumulate -> partial[b][128].  (R9-proven)
// ---------------------------------------------------------------------------
__global__ __launch_bounds__(256) void k1_gather_ln_pool(
    const float* __restrict__ x,
    const float* __restrict__ g_enc, const float* __restrict__ b_enc,
    const int* __restrict__ node_pos, const int* __restrict__ node_ids,
    float* __restrict__ partial)
{
    __shared__ float lds[4 * 128];
    const int tid   = threadIdx.x;
    const int lane  = tid & 63;
    const int wid   = tid >> 6;
    const int j     = lane & 15;   // channel sublane
    const int q     = lane >> 4;   // quarter (row within 4-row batch)
    const int b     = blockIdx.x;
    const int t     = b >> 6;      // 64 blocks per t
    const int chunk = b & 63;
    const int tP    = t * P_;
    const float* xt = x + (size_t)t * TOK_ * D_;

    const f32x4 g0  = *(const f32x4*)(g_enc + 8 * j);
    const f32x4 g1  = *(const f32x4*)(g_enc + 8 * j + 4);
    const f32x4 bb0 = *(const f32x4*)(b_enc + 8 * j);
    const f32x4 bb1 = *(const f32x4*)(b_enc + 8 * j + 4);
    const float G = g0.x + g0.y + g0.z + g0.w + g1.x + g1.y + g1.z + g1.w;
    const float B = bb0.x + bb0.y + bb0.z + bb0.w + bb1.x + bb1.y + bb1.z + bb1.w;

    float acc[L_];
#pragma unroll
    for (int ll = 0; ll < L_; ++ll) acc[ll] = 0.f;

#pragma unroll
    for (int pass = 0; pass < 2; ++pass) {
        const int pbase = chunk * 128 + pass * 64 + wid * 16;
        const int posv = node_pos[tP + pbase + j];
        const int nidv = node_ids[tP + pbase + j];

        f32x4 va[4], vb[4];
#pragma unroll
        for (int i = 0; i < 4; ++i) {
            const int p = __shfl(posv, i * 4 + q);
            const float* row = xt + (size_t)p * D_ + 8 * j;
            va[i] = *(const f32x4*)(row);
            vb[i] = *(const f32x4*)(row + 4);
        }
#pragma unroll
        for (int i = 0; i < 4; ++i) {
            const f32x4 a = va[i], c = vb[i];
            float s  = a.x + a.y + a.z + a.w + c.x + c.y + c.z + c.w;
            float ss = a.x*a.x + a.y*a.y + a.z*a.z + a.w*a.w
                     + c.x*c.x + c.y*c.y + c.z*c.z + c.w*c.w;
            float dot = a.x*g0.x + a.y*g0.y + a.z*g0.z + a.w*g0.w
                      + c.x*g1.x + c.y*g1.y + c.z*g1.z + c.w*g1.w;
#pragma unroll
            for (int m = 1; m < 16; m <<= 1) {
                s  += __shfl_xor(s, m);
                ss += __shfl_xor(ss, m);
            }
            const float mean = s * (1.f / 128.f);
            const float rstd = rsqrtf(ss * (1.f / 128.f) - mean * mean + 1e-5f);
            const float srow = (dot - mean * G) * rstd + B;
            const int l = __shfl(nidv, i * 4 + q) >> 12;
#pragma unroll
            for (int ll = 0; ll < L_; ++ll) acc[ll] += (ll == l) ? srow : 0.f;
        }
    }

#pragma unroll
    for (int ll = 0; ll < L_; ++ll) {
        acc[ll] += __shfl_xor(acc[ll], 16);
        acc[ll] += __shfl_xor(acc[ll], 32);
    }
    if (lane < 16) {
#pragma unroll
        for (int ll = 0; ll < L_; ++ll) lds[wid * 128 + ll * 16 + j] = acc[ll];
    }
    __syncthreads();
    if (tid < 128) {
        const float sum = lds[tid] + lds[128 + tid] + lds[256 + tid] + lds[384 + tid];
        partial[(size_t)b * 128 + tid] = sum;   // deterministic overwrite
    }
}

// ---------------------------------------------------------------------------
// Kernel 2: reduce 64 partials per t, scale, LN over 128 (g_fin,b_fin),
// LN over 16-element groups (g_dec,b_dec) -> decoded[t*128 + l*16 + c]
// ---------------------------------------------------------------------------
__global__ __launch_bounds__(64) void k2_finalize(
    const float* __restrict__ partial,
    const float* __restrict__ g_fin, const float* __restrict__ b_fin,
    const float* __restrict__ g_dec, const float* __restrict__ b_dec,
    float* __restrict__ decoded)
{
    const int t = blockIdx.x;
    const int lane = threadIdx.x;
    const float* pb = partial + (size_t)t * BLOCKS_PER_T * 128;
    float a0 = 0.f, a1 = 0.f;
#pragma unroll 8
    for (int k = 0; k < BLOCKS_PER_T; ++k) {
        a0 += pb[k * 128 + lane];
        a1 += pb[k * 128 + 64 + lane];
    }
    a0 *= (1.f / 32768.f);   // /4096 scatter slots /8 pooled
    a1 *= (1.f / 32768.f);

    float s = a0 + a1, ss = a0 * a0 + a1 * a1;
#pragma unroll
    for (int m = 1; m < 64; m <<= 1) {
        s  += __shfl_xor(s, m);
        ss += __shfl_xor(ss, m);
    }
    const float mean = s * (1.f / 128.f);
    const float rstd = rsqrtf(ss * (1.f / 128.f) - mean * mean + 1e-5f);
    const float c0 = (a0 - mean) * rstd * g_fin[lane]      + b_fin[lane];
    const float c1 = (a1 - mean) * rstd * g_fin[lane + 64] + b_fin[lane + 64];

    float s0 = c0, q0 = c0 * c0, s1 = c1, q1 = c1 * c1;
#pragma unroll
    for (int m = 1; m < 16; m <<= 1) {
        s0 += __shfl_xor(s0, m); q0 += __shfl_xor(q0, m);
        s1 += __shfl_xor(s1, m); q1 += __shfl_xor(q1, m);
    }
    const float m0 = s0 * (1.f / 16.f), m1 = s1 * (1.f / 16.f);
    const float r0 = rsqrtf(q0 * (1.f / 16.f) - m0 * m0 + 1e-5f);
    const float r1 = rsqrtf(q1 * (1.f / 16.f) - m1 * m1 + 1e-5f);
    const int c = lane & 15;
    const float gd = g_dec[c], bd = b_dec[c];
    decoded[t * 128 + lane]      = (c0 - m0) * r0 * gd + bd;
    decoded[t * 128 + 64 + lane] = (c1 - m1) * r1 * gd + bd;
}

// ---------------------------------------------------------------------------
// Kernel 3: out[t,n,d] = decoded[t, n>>12, d>>3].
// WAVE-CONTIGUOUS streaming: each wave owns a contiguous 128 KB chunk and
// walks it in sequential 1 KB bursts (f32x4 idx = b*32768 + w*8192 + it*64
// + lane), so consecutive wave instructions hit the same/adjacent HBM rows
// (old layout strode 4 KB between a wave's instructions -> row thrash).
// Per-thread value is still constant: idx & 31 = lane & 31.
// 512 blocks, nt-stores (R6 A/B: nt > plain).
// ---------------------------------------------------------------------------
__global__ __launch_bounds__(256) void k3_broadcast(
    const float* __restrict__ decoded, f32x4* __restrict__ out)
{
    const int tid  = threadIdx.x;
    const int lane = tid & 63;
    const int wid  = tid >> 6;
    const int b    = blockIdx.x;
    const int t    = b >> 5;
    const int s    = b & 31;                      // 1024-row slice, one l = s>>2
    const int l    = s >> 2;
    const float val = decoded[(t << 7) + (l << 4) + ((lane & 31) >> 1)];
    const f32x4 v4 = {val, val, val, val};
    // wave chunk: 8192 f32x4 = 128 KB, walked sequentially
    f32x4* p = out + (((size_t)t << 20) + ((size_t)s << 15) + (wid << 13) + lane);
#pragma unroll 8
    for (int it = 0; it < 128; ++it)
        __builtin_nontemporal_store(v4, p + (it << 6));
}

extern "C" void kernel_launch(void* const* d_in, const int* in_sizes, int n_in,
                              void* d_out, int out_size, void* d_ws, size_t ws_size,
                              hipStream_t stream)
{
    const float* x      = (const float*)d_in[0];
    const float* g_enc  = (const float*)d_in[1];
    const float* b_enc  = (const float*)d_in[2];
    const float* g_fin  = (const float*)d_in[3];
    const float* b_fin  = (const float*)d_in[4];
    const float* g_dec  = (const float*)d_in[5];
    const float* b_dec  = (const float*)d_in[6];
    const int*   node_pos = (const int*)d_in[7];
    const int*   node_ids = (const int*)d_in[8];

    float* partial = (float*)d_ws;                         // 1024*128 f32 = 512 KB
    float* decoded = partial + (size_t)K1_BLOCKS * 128;    // 2048 f32
    float* out = (float*)d_out;

    hipLaunchKernelGGL(k1_gather_ln_pool, dim3(K1_BLOCKS), dim3(256), 0, stream,
                       x, g_enc, b_enc, node_pos, node_ids, partial);
    hipLaunchKernelGGL(k2_finalize, dim3(T_), dim3(64), 0, stream,
                       partial, g_fin, b_fin, g_dec, b_dec, decoded);
    hipLaunchKernelGGL(k3_broadcast, dim3(K3_BLOCKS), dim3(256), 0, stream,
                       decoded, (f32x4*)out);
}

// Round 11
// 68.460 us; speedup vs baseline: 4.4517x; 1.0353x over previous
//
#include <hip/hip_runtime.h>

// Problem constants (fixed by setup_inputs)
#define T_   16
#define TOK_ 16384
#define P_   8192
#define N_   32768
#define D_   128
#define L_   8
#define C_   16

typedef float f32x4 __attribute__((ext_vector_type(4)));

constexpr int K1_BLOCKS     = 1024;  // 4/CU
constexpr int BLOCKS_PER_T  = 64;    // K1 blocks per timestamp
constexpr int K3_BLOCKS     = 512;   // 2/CU; each block streams 512 KB

// ---------------------------------------------------------------------------
// Kernel 1: gather x rows at node_pos, LN(D=128) with algebraically-fused
// 8->1 pool, per-group-l accumulate -> partial[b][128].
// This round: BOTH passes' index loads and all 16 gather f32x4 loads issue
// up-front -> single memory round-trip per wave (was two serialized).
// ---------------------------------------------------------------------------
__global__ __launch_bounds__(256) void k1_gather_ln_pool(
    const float* __restrict__ x,
    const float* __restrict__ g_enc, const float* __restrict__ b_enc,
    const int* __restrict__ node_pos, const int* __restrict__ node_ids,
    float* __restrict__ partial)
{
    __shared__ float lds[4 * 128];
    const int tid   = threadIdx.x;
    const int lane  = tid & 63;
    const int wid   = tid >> 6;
    const int j     = lane & 15;   // channel sublane
    const int q     = lane >> 4;   // quarter (row within 4-row batch)
    const int b     = blockIdx.x;
    const int t     = b >> 6;      // 64 blocks per t
    const int chunk = b & 63;
    const int tP    = t * P_;
    const int pbase = chunk * 128 + wid * 16;   // pass 0 rows; pass 1 = +64
    const float* xt = x + (size_t)t * TOK_ * D_;

    const f32x4 g0  = *(const f32x4*)(g_enc + 8 * j);
    const f32x4 g1  = *(const f32x4*)(g_enc + 8 * j + 4);
    const f32x4 bb0 = *(const f32x4*)(b_enc + 8 * j);
    const f32x4 bb1 = *(const f32x4*)(b_enc + 8 * j + 4);
    const float G = g0.x + g0.y + g0.z + g0.w + g1.x + g1.y + g1.z + g1.w;
    const float B = bb0.x + bb0.y + bb0.z + bb0.w + bb1.x + bb1.y + bb1.z + bb1.w;

    // both passes' row indices up front (lanes 0..15 hold them)
    int posv[2], nidv[2];
    posv[0] = node_pos[tP + pbase + j];
    nidv[0] = node_ids[tP + pbase + j];
    posv[1] = node_pos[tP + pbase + 64 + j];
    nidv[1] = node_ids[tP + pbase + 64 + j];

    // issue ALL 16 gather loads up-front (row r = i*4+q of each pass)
    f32x4 va[8], vb[8];
#pragma unroll
    for (int pass = 0; pass < 2; ++pass) {
#pragma unroll
        for (int i = 0; i < 4; ++i) {
            const int p = __shfl(posv[pass], i * 4 + q);
            const float* row = xt + (size_t)p * D_ + 8 * j;
            va[pass * 4 + i] = *(const f32x4*)(row);
            vb[pass * 4 + i] = *(const f32x4*)(row + 4);
        }
    }

    float acc[L_];
#pragma unroll
    for (int ll = 0; ll < L_; ++ll) acc[ll] = 0.f;

#pragma unroll
    for (int pass = 0; pass < 2; ++pass) {
#pragma unroll
        for (int i = 0; i < 4; ++i) {
            const f32x4 a = va[pass * 4 + i], c = vb[pass * 4 + i];
            float s  = a.x + a.y + a.z + a.w + c.x + c.y + c.z + c.w;
            float ss = a.x*a.x + a.y*a.y + a.z*a.z + a.w*a.w
                     + c.x*c.x + c.y*c.y + c.z*c.z + c.w*c.w;
            float dot = a.x*g0.x + a.y*g0.y + a.z*g0.z + a.w*g0.w
                      + c.x*g1.x + c.y*g1.y + c.z*g1.z + c.w*g1.w;
#pragma unroll
            for (int m = 1; m < 16; m <<= 1) {
                s  += __shfl_xor(s, m);
                ss += __shfl_xor(ss, m);
            }
            const float mean = s * (1.f / 128.f);
            const float rstd = rsqrtf(ss * (1.f / 128.f) - mean * mean + 1e-5f);
            const float srow = (dot - mean * G) * rstd + B;
            const int l = __shfl(nidv[pass], i * 4 + q) >> 12;
#pragma unroll
            for (int ll = 0; ll < L_; ++ll) acc[ll] += (ll == l) ? srow : 0.f;
        }
    }

    // combine quarters (lanes j, j+16, j+32, j+48 share channel j)
#pragma unroll
    for (int ll = 0; ll < L_; ++ll) {
        acc[ll] += __shfl_xor(acc[ll], 16);
        acc[ll] += __shfl_xor(acc[ll], 32);
    }
    if (lane < 16) {
#pragma unroll
        for (int ll = 0; ll < L_; ++ll) lds[wid * 128 + ll * 16 + j] = acc[ll];
    }
    __syncthreads();
    if (tid < 128) {
        const float sum = lds[tid] + lds[128 + tid] + lds[256 + tid] + lds[384 + tid];
        partial[(size_t)b * 128 + tid] = sum;   // deterministic overwrite
    }
}

// ---------------------------------------------------------------------------
// Kernel 3 (fused finalize + broadcast), replaces K2+K3:
// Each block REDUNDANTLY finalizes its t (reads 64 partial chunks = 32 KB,
// L2-hot; no sync primitives — the K1->K3 kernel boundary guarantees
// visibility; every block computes bit-identical dec[] from identical
// inputs -> deterministic). Then streams its 512 KB slice wave-contiguously
// with nt f32x4 stores (R6 A/B: nt > plain; R10 layout).
// ---------------------------------------------------------------------------
__global__ __launch_bounds__(256) void k3_finalize_broadcast(
    const float* __restrict__ partial,
    const float* __restrict__ g_fin, const float* __restrict__ b_fin,
    const float* __restrict__ g_dec, const float* __restrict__ b_dec,
    f32x4* __restrict__ out)
{
    __shared__ float hsum[2][128];
    __shared__ float dec[128];
    const int tid  = threadIdx.x;
    const int lane = tid & 63;
    const int wid  = tid >> 6;
    const int b    = blockIdx.x;
    const int t    = b >> 5;
    const int s    = b & 31;                     // 1024-row slice, one l = s>>2

    // ---- per-block finalize ------------------------------------------------
    {
        const float* pb = partial + (size_t)t * BLOCKS_PER_T * 128;
        const int ch = tid & 127, h = tid >> 7;  // h in {0,1}: 32 chunks each
        float a = 0.f;
#pragma unroll 8
        for (int k = 0; k < 32; ++k)
            a += pb[(h * 32 + k) * 128 + ch];
        hsum[h][ch] = a;
        __syncthreads();
        if (wid == 0) {
            float c0 = (hsum[0][lane] + hsum[1][lane]) * (1.f / 32768.f);
            float c1 = (hsum[0][64 + lane] + hsum[1][64 + lane]) * (1.f / 32768.f);
            float sm = c0 + c1, ss = c0 * c0 + c1 * c1;
#pragma unroll
            for (int m = 1; m < 64; m <<= 1) {
                sm += __shfl_xor(sm, m);
                ss += __shfl_xor(ss, m);
            }
            const float mean = sm * (1.f / 128.f);
            const float rstd = rsqrtf(ss * (1.f / 128.f) - mean * mean + 1e-5f);
            const float e0 = (c0 - mean) * rstd * g_fin[lane]      + b_fin[lane];
            const float e1 = (c1 - mean) * rstd * g_fin[lane + 64] + b_fin[lane + 64];

            float s0 = e0, q0 = e0 * e0, s1 = e1, q1 = e1 * e1;
#pragma unroll
            for (int m = 1; m < 16; m <<= 1) {
                s0 += __shfl_xor(s0, m); q0 += __shfl_xor(q0, m);
                s1 += __shfl_xor(s1, m); q1 += __shfl_xor(q1, m);
            }
            const float m0 = s0 * (1.f / 16.f), m1 = s1 * (1.f / 16.f);
            const float r0 = rsqrtf(q0 * (1.f / 16.f) - m0 * m0 + 1e-5f);
            const float r1 = rsqrtf(q1 * (1.f / 16.f) - m1 * m1 + 1e-5f);
            const int c = lane & 15;
            const float gd = g_dec[c], bd = b_dec[c];
            dec[lane]      = (e0 - m0) * r0 * gd + bd;
            dec[64 + lane] = (e1 - m1) * r1 * gd + bd;
        }
        __syncthreads();
    }

    // ---- stream 512 KB slice (wave-contiguous, nt) -------------------------
    const int l = s >> 2;
    const float val = dec[(l << 4) + ((lane & 31) >> 1)];
    const f32x4 v4 = {val, val, val, val};
    f32x4* p = out + (((size_t)t << 20) + ((size_t)s << 15) + (wid << 13) + lane);
#pragma unroll 8
    for (int it = 0; it < 128; ++it)
        __builtin_nontemporal_store(v4, p + (it << 6));
}

extern "C" void kernel_launch(void* const* d_in, const int* in_sizes, int n_in,
                              void* d_out, int out_size, void* d_ws, size_t ws_size,
                              hipStream_t stream)
{
    const float* x      = (const float*)d_in[0];
    const float* g_enc  = (const float*)d_in[1];
    const float* b_enc  = (const float*)d_in[2];
    const float* g_fin  = (const float*)d_in[3];
    const float* b_fin  = (const float*)d_in[4];
    const float* g_dec  = (const float*)d_in[5];
    const float* b_dec  = (const float*)d_in[6];
    const int*   node_pos = (const int*)d_in[7];
    const int*   node_ids = (const int*)d_in[8];

    float* partial = (float*)d_ws;      // 1024*128 f32 = 512 KB
    float* out     = (float*)d_out;

    hipLaunchKernelGGL(k1_gather_ln_pool, dim3(K1_BLOCKS), dim3(256), 0, stream,
                       x, g_enc, b_enc, node_pos, node_ids, partial);
    hipLaunchKernelGGL(k3_finalize_broadcast, dim3(K3_BLOCKS), dim3(256), 0, stream,
                       partial, g_fin, b_fin, g_dec, b_dec, (f32x4*)out);
}